// Round 10
// baseline (446.001 us; speedup 1.0000x reference)
//
#include <hip/hip_runtime.h>

typedef unsigned short u16;
typedef __attribute__((ext_vector_type(8))) short vbf16x8;   // 8 bf16 (4 VGPRs)
typedef __attribute__((ext_vector_type(4))) float vf32x4;    // MFMA acc frag

__device__ __forceinline__ float bf2f(u16 u) {
    union { unsigned int i; float f; } v; v.i = ((unsigned int)u) << 16; return v.f;
}
__device__ __forceinline__ u16 f2bf(float f) {
    union { float f; unsigned int i; } v; v.f = f;
    return (u16)((v.i + 0x7fffu + ((v.i >> 16) & 1u)) >> 16);  // RNE
}

// Direct global B-fragment read (replaces LDS-staged weight tile):
// identical bytes to the old swizzled-LDS read — the XOR swizzle cancels:
// WS[(n*16 + ((ks*4+kq)^r15))*8] held WT[n*128 + ks*32 + kq*8] for n=nt*16+r15.
// Weights are 32 KB/matrix, re-read by every block -> L1/L2-resident.
// Dropping LDS lifts the 32-64 KB/block occupancy cap on latency-bound GEMMs.
__device__ __forceinline__ vbf16x8 bfrag(const u16* WT, int nt, int r15, int ks, int kq) {
    return *(const vbf16x8*)(WT + (size_t)(nt * 16 + r15) * 128 + ks * 32 + kq * 8);
}

struct TPack { const float* src[9]; u16* dst[9]; };

// ============== bucketed CSR build constants ==============
#define NBUK 256
#define NBLK_BIN 256
#define SCAP 24
#define OVFCAP 32768
#define PACK_SH 17   // staged word = (local_key << 17) | val ; val < 2^17

// ---- 9 weight transposes (576 blocks) + ovfn zero (replaces memset) ----
__global__ __launch_bounds__(256) void wtp(TPack p, int* __restrict__ ovfn) {
    int b = blockIdx.x;
    if (b == 0 && threadIdx.x < 2) ovfn[threadIdx.x] = 0;
    int mat = b >> 6;
    const float* s = p.src[mat];
    u16* d = p.dst[mat];
    int i = (b & 63) * 256 + threadIdx.x;
    int k = i >> 7, n = i & 127;
    d[(size_t)n * 128 + k] = f2bf(s[(size_t)k * 128 + n]);
}

// ===== mega2: doc GEMM tiles ∥ edge bin-scatter ∥ author gather ==========
// Contiguous block ranges (r6 layout — measured best). GEMM branch reads
// weights direct from global (no LDS); only binning uses 1 KB LDS.
__global__ __launch_bounds__(256) void mega2(
    const float* __restrict__ A1f, const u16* __restrict__ W1T,
    const float* __restrict__ biasd, u16* __restrict__ xdoc, int M, int BD,
    const float* __restrict__ emb, const int* __restrict__ ids,
    u16* __restrict__ xauth, int NA,
    const int* __restrict__ src, const int* __restrict__ dst,
    unsigned* __restrict__ stageD, unsigned* __restrict__ stageA,
    int* __restrict__ cntD, int* __restrict__ cntA,
    uint2* __restrict__ ovfD, uint2* __restrict__ ovfA, int* __restrict__ ovfn,
    int E, int shD, int shA) {
    __shared__ int lcnt[NBUK];          // 1 KB — binning only
    const int b = blockIdx.x;
    const int tid = threadIdx.x;

    if (b < BD) {                          // ---- doc encoder GEMM tile ----
        const int lane = tid & 63, wave = tid >> 6;
        const int r15 = lane & 15, kq = lane >> 4;
        const int rowbase = b * 128 + wave * 32;
        const int m0 = rowbase + r15, m1 = rowbase + 16 + r15;
        const bool v0 = rowbase < M, v1 = rowbase + 16 < M;

        vf32x4 acc0[8], acc1[8];
#pragma unroll
        for (int i = 0; i < 8; ++i) { acc0[i] = (vf32x4)(0.0f); acc1[i] = (vf32x4)(0.0f); }

#pragma unroll
        for (int ks = 0; ks < 4; ++ks) {
            vbf16x8 a0 = (vbf16x8)(short)0, a1 = (vbf16x8)(short)0;
            if (v0) {
                const float* p = A1f + (size_t)m0 * 128 + ks * 32 + kq * 8;
                float4 lo = *(const float4*)p, hi = *(const float4*)(p + 4);
                a0[0] = (short)f2bf(lo.x); a0[1] = (short)f2bf(lo.y);
                a0[2] = (short)f2bf(lo.z); a0[3] = (short)f2bf(lo.w);
                a0[4] = (short)f2bf(hi.x); a0[5] = (short)f2bf(hi.y);
                a0[6] = (short)f2bf(hi.z); a0[7] = (short)f2bf(hi.w);
            }
            if (v1) {
                const float* p = A1f + (size_t)m1 * 128 + ks * 32 + kq * 8;
                float4 lo = *(const float4*)p, hi = *(const float4*)(p + 4);
                a1[0] = (short)f2bf(lo.x); a1[1] = (short)f2bf(lo.y);
                a1[2] = (short)f2bf(lo.z); a1[3] = (short)f2bf(lo.w);
                a1[4] = (short)f2bf(hi.x); a1[5] = (short)f2bf(hi.y);
                a1[6] = (short)f2bf(hi.z); a1[7] = (short)f2bf(hi.w);
            }
#pragma unroll
            for (int nt = 0; nt < 8; ++nt) {
                vbf16x8 bb = bfrag(W1T, nt, r15, ks, kq);
                acc0[nt] = __builtin_amdgcn_mfma_f32_16x16x32_bf16(a0, bb, acc0[nt], 0, 0, 0);
                acc1[nt] = __builtin_amdgcn_mfma_f32_16x16x32_bf16(a1, bb, acc1[nt], 0, 0, 0);
            }
        }

#pragma unroll
        for (int nt = 0; nt < 8; ++nt) {
            const float bv = biasd[nt * 16 + r15];
#pragma unroll
            for (int r = 0; r < 4; ++r) {
                if (v0) xdoc[(size_t)(rowbase + kq * 4 + r) * 128 + nt * 16 + r15] =
                    f2bf(acc0[nt][r] + bv);
                if (v1) xdoc[(size_t)(rowbase + 16 + kq * 4 + r) * 128 + nt * 16 + r15] =
                    f2bf(acc1[nt][r] + bv);
            }
        }
        return;
    }

    if (b < BD + 2 * NBLK_BIN) {           // ---- edge binning ----
        int bb = b - BD;
        const bool isD = bb < NBLK_BIN;
        const int blk = isD ? bb : bb - NBLK_BIN;
        const int* key = isD ? src : dst;
        const int* val = isD ? dst : src;
        const int shift = isD ? shD : shA;
        unsigned* stage = isD ? stageD : stageA;
        int* cnt = isD ? cntD : cntA;
        uint2* ovf = isD ? ovfD : ovfA;
        int* on = ovfn + (isD ? 0 : 1);
        const int per = (E + NBLK_BIN - 1) / NBLK_BIN;
        const int beg = blk * per;
        const int end = min(beg + per, E);
        for (int i = tid; i < NBUK; i += 256) lcnt[i] = 0;
        __syncthreads();
        for (int e = beg + tid; e < end; e += 256) {
            int k = key[e], v = val[e];
            int bkt = k >> shift;
            int slot = atomicAdd(&lcnt[bkt], 1);
            if (slot < SCAP) {
                unsigned local = (unsigned)(k - (bkt << shift));
                stage[((size_t)bkt * NBLK_BIN + blk) * SCAP + slot] =
                    (local << PACK_SH) | (unsigned)v;
            } else {                       // rare: spill to overflow list
                int oi = atomicAdd(on, 1);
                if (oi < OVFCAP) ovf[oi] = make_uint2((unsigned)k, (unsigned)v);
            }
        }
        __syncthreads();
        for (int i = tid; i < NBUK; i += 256)
            cnt[(size_t)i * NBLK_BIN + blk] = min(lcnt[i], SCAP);
        return;
    }

    // ---- author row gather ----
    int gid = (b - BD - 2 * NBLK_BIN) * 256 + tid;
    if (gid >= NA * 16) return;
    int n = gid >> 4, f = gid & 15;
    int id = ids[n];
    const float* s = emb + (size_t)id * 128 + f * 8;
    float4 lo = *(const float4*)(s);
    float4 hi = *(const float4*)(s + 4);
    u16 o[8] = {f2bf(lo.x), f2bf(lo.y), f2bf(lo.z), f2bf(lo.w),
                f2bf(hi.x), f2bf(hi.y), f2bf(hi.z), f2bf(hi.w)};
    *(uint4*)(xauth + (size_t)n * 128 + f * 8) = *(const uint4*)o;
}

// ---- per-bucket LDS histogram -> per-node counts + per-bucket totals ----
__global__ __launch_bounds__(256) void bucket_count2(
    const unsigned* __restrict__ stageD, const unsigned* __restrict__ stageA,
    const int* __restrict__ cntD, const int* __restrict__ cntA,
    const uint2* __restrict__ ovfD, const uint2* __restrict__ ovfA,
    const int* __restrict__ ovfn,
    int* __restrict__ cnt_d, int* __restrict__ cnt_a, int* __restrict__ btot,
    int ND, int NA, int shD, int shA) {
    __shared__ int hist[1024];
    __shared__ int segc[NBLK_BIN];
    __shared__ int red[256];
    const bool isD = (int)blockIdx.x < NBUK;
    const int b = isD ? (int)blockIdx.x : (int)blockIdx.x - NBUK;
    const int sh = isD ? shD : shA;
    const int N = isD ? ND : NA;
    const int base = b << sh;
    const int range = min(1 << sh, N - base);
    const int tid = threadIdx.x;
    if (range <= 0) { if (tid == 0) btot[blockIdx.x] = 0; return; }
    const unsigned* stage = (isD ? stageD : stageA) + (size_t)b * NBLK_BIN * SCAP;
    const int* scnt = (isD ? cntD : cntA) + (size_t)b * NBLK_BIN;
    const uint2* ovf = isD ? ovfD : ovfA;
    const int nov = min(ovfn[isD ? 0 : 1], OVFCAP);
    int* out = isD ? cnt_d : cnt_a;
    for (int i = tid; i < (1 << sh); i += 256) hist[i] = 0;
    segc[tid] = scnt[tid];
    __syncthreads();
    int my = 0;
    for (int j = tid; j < NBLK_BIN * SCAP; j += 256) {
        int seg = j / SCAP, slot = j - seg * SCAP;
        if (slot < segc[seg]) { atomicAdd(&hist[stage[j] >> PACK_SH], 1); ++my; }
    }
    for (int i = tid; i < nov; i += 256) {
        int k = (int)ovf[i].x;
        if ((k >> sh) == b) { atomicAdd(&hist[k - base], 1); ++my; }
    }
    red[tid] = my;
    __syncthreads();
    for (int s = 128; s > 0; s >>= 1) {
        if (tid < s) red[tid] += red[tid + s];
        __syncthreads();
    }
    if (tid == 0) btot[blockIdx.x] = red[0];
    for (int i = tid; i < range; i += 256) out[base + i] = hist[i];
}

// ---- single-block exclusive scan over per-bucket totals (both sides) ----
__global__ __launch_bounds__(256) void scanb(int* __restrict__ btot) {
    __shared__ int sh[256];
    const int tid = threadIdx.x;
    for (int seg = 0; seg < 2; ++seg) {
        int* p = btot + seg * NBUK;
        int v = p[tid];
        sh[tid] = v;
        __syncthreads();
        for (int off = 1; off < 256; off <<= 1) {
            int t = tid >= off ? sh[tid - off] : 0;
            __syncthreads();
            sh[tid] += t;
            __syncthreads();
        }
        p[tid] = sh[tid] - v;   // exclusive
        __syncthreads();
    }
}

// ---- per-bucket: node-level LDS scan -> offs, then nbr fill -------------
__global__ __launch_bounds__(256) void bucket_fill3(
    const unsigned* __restrict__ stageD, const unsigned* __restrict__ stageA,
    const int* __restrict__ cntD, const int* __restrict__ cntA,
    const uint2* __restrict__ ovfD, const uint2* __restrict__ ovfA,
    const int* __restrict__ ovfn,
    const int* __restrict__ cnt_d, const int* __restrict__ cnt_a,
    const int* __restrict__ btot,
    int* __restrict__ offs_d, int* __restrict__ offs_a,
    int* __restrict__ nbr_d, int* __restrict__ nbr_a,
    int ND, int NA, int shD, int shA) {
    __shared__ int lcur[1024];
    __shared__ int segc[NBLK_BIN];
    __shared__ int sh[256];
    __shared__ int carry;
    const bool isD = (int)blockIdx.x < NBUK;
    const int b = isD ? (int)blockIdx.x : (int)blockIdx.x - NBUK;
    const int shft = isD ? shD : shA;
    const int N = isD ? ND : NA;
    const int base = b << shft;
    const int range = min(1 << shft, N - base);
    if (range <= 0) return;
    const unsigned* stage = (isD ? stageD : stageA) + (size_t)b * NBLK_BIN * SCAP;
    const int* scnt = (isD ? cntD : cntA) + (size_t)b * NBLK_BIN;
    const uint2* ovf = isD ? ovfD : ovfA;
    const int nov = min(ovfn[isD ? 0 : 1], OVFCAP);
    const int* cnodes = isD ? cnt_d : cnt_a;
    int* offs = isD ? offs_d : offs_a;
    int* nbr = isD ? nbr_d : nbr_a;
    const int tid = threadIdx.x;
    segc[tid] = scnt[tid];
    if (tid == 0) carry = btot[blockIdx.x];   // exclusive bucket base
    __syncthreads();
    // chunked exclusive scan of per-node counts -> offs + LDS cursors
    for (int c0 = 0; c0 < range; c0 += 256) {
        int i = c0 + tid;
        int v = (i < range) ? cnodes[base + i] : 0;
        sh[tid] = v;
        __syncthreads();
        for (int off = 1; off < 256; off <<= 1) {
            int t = tid >= off ? sh[tid - off] : 0;
            __syncthreads();
            sh[tid] += t;
            __syncthreads();
        }
        if (i < range) {
            int ex = carry + sh[tid] - v;
            lcur[i] = ex;
            offs[base + i] = ex;
        }
        __syncthreads();
        if (tid == 255) carry += sh[255];
        __syncthreads();
    }
    if (tid == 0) offs[base + range] = carry;  // duplicate of next bucket's base
    __syncthreads();
    // fill
    for (int j = tid; j < NBLK_BIN * SCAP; j += 256) {
        int seg = j / SCAP, slot = j - seg * SCAP;
        if (slot < segc[seg]) {
            unsigned pk = stage[j];
            int local = pk >> PACK_SH;
            int v = (int)(pk & ((1u << PACK_SH) - 1u));
            nbr[atomicAdd(&lcur[local], 1)] = v;
        }
    }
    for (int i = tid; i < nov; i += 256) {
        int k = (int)ovf[i].x;
        if ((k >> shft) == b)
            nbr[atomicAdd(&lcur[k - base], 1)] = (int)ovf[i].y;
    }
}

// ================= fused gather mean-aggregation (both sides) =============
__global__ __launch_bounds__(256) void agg_mean2(
    const u16* __restrict__ xa, const int* __restrict__ offs_a,
    const int* __restrict__ nbr_a, u16* __restrict__ outa, int NA,
    const u16* __restrict__ xd, const int* __restrict__ offs_d,
    const int* __restrict__ nbr_d, u16* __restrict__ outd, int ND) {
    int gid = blockIdx.x * 256 + threadIdx.x;
    int node = gid >> 4, f = gid & 15;
    int lane = threadIdx.x & 63;
    int gbase = lane & 48;                 // group base lane within wave
    const u16* x; const int* offs; const int* nbr; u16* out;
    if (node < NA) { x = xa; offs = offs_a; nbr = nbr_a; out = outa; }
    else {
        node -= NA;
        if (node >= ND) return;
        x = xd; offs = offs_d; nbr = nbr_d; out = outd;
    }
    int beg = offs[node], end = offs[node + 1];
    float acc[8] = {0, 0, 0, 0, 0, 0, 0, 0};

    for (int i = beg; i < end; i += 16) {
        int cnt = end - i; if (cnt > 16) cnt = 16;
        int myn = (i + f < end) ? nbr[i + f] : 0;
        int t = 0;
        for (; t + 3 < cnt; t += 4) {      // 4 row-gathers in flight
            int i0 = __shfl(myn, gbase + t);
            int i1 = __shfl(myn, gbase + t + 1);
            int i2 = __shfl(myn, gbase + t + 2);
            int i3 = __shfl(myn, gbase + t + 3);
            uint4 q0 = *(const uint4*)(x + (size_t)i0 * 128 + f * 8);
            uint4 q1 = *(const uint4*)(x + (size_t)i1 * 128 + f * 8);
            uint4 q2 = *(const uint4*)(x + (size_t)i2 * 128 + f * 8);
            uint4 q3 = *(const uint4*)(x + (size_t)i3 * 128 + f * 8);
            acc[0] += bf2f((u16)(q0.x & 0xffff)) + bf2f((u16)(q1.x & 0xffff))
                    + bf2f((u16)(q2.x & 0xffff)) + bf2f((u16)(q3.x & 0xffff));
            acc[1] += bf2f((u16)(q0.x >> 16))    + bf2f((u16)(q1.x >> 16))
                    + bf2f((u16)(q2.x >> 16))    + bf2f((u16)(q3.x >> 16));
            acc[2] += bf2f((u16)(q0.y & 0xffff)) + bf2f((u16)(q1.y & 0xffff))
                    + bf2f((u16)(q2.y & 0xffff)) + bf2f((u16)(q3.y & 0xffff));
            acc[3] += bf2f((u16)(q0.y >> 16))    + bf2f((u16)(q1.y >> 16))
                    + bf2f((u16)(q2.y >> 16))    + bf2f((u16)(q3.y >> 16));
            acc[4] += bf2f((u16)(q0.z & 0xffff)) + bf2f((u16)(q1.z & 0xffff))
                    + bf2f((u16)(q2.z & 0xffff)) + bf2f((u16)(q3.z & 0xffff));
            acc[5] += bf2f((u16)(q0.z >> 16))    + bf2f((u16)(q1.z >> 16))
                    + bf2f((u16)(q2.z >> 16))    + bf2f((u16)(q3.z >> 16));
            acc[6] += bf2f((u16)(q0.w & 0xffff)) + bf2f((u16)(q1.w & 0xffff))
                    + bf2f((u16)(q2.w & 0xffff)) + bf2f((u16)(q3.w & 0xffff));
            acc[7] += bf2f((u16)(q0.w >> 16))    + bf2f((u16)(q1.w >> 16))
                    + bf2f((u16)(q2.w >> 16))    + bf2f((u16)(q3.w >> 16));
        }
        for (; t < cnt; ++t) {
            int i0 = __shfl(myn, gbase + t);
            uint4 q0 = *(const uint4*)(x + (size_t)i0 * 128 + f * 8);
            acc[0] += bf2f((u16)(q0.x & 0xffff));
            acc[1] += bf2f((u16)(q0.x >> 16));
            acc[2] += bf2f((u16)(q0.y & 0xffff));
            acc[3] += bf2f((u16)(q0.y >> 16));
            acc[4] += bf2f((u16)(q0.z & 0xffff));
            acc[5] += bf2f((u16)(q0.z >> 16));
            acc[6] += bf2f((u16)(q0.w & 0xffff));
            acc[7] += bf2f((u16)(q0.w >> 16));
        }
    }
    float inv = 1.0f / fmaxf((float)(end - beg), 1.0f);
    u16 o[8];
#pragma unroll
    for (int j = 0; j < 8; ++j) o[j] = f2bf(acc[j] * inv);
    *(uint4*)(out + (size_t)node * 128 + f * 8) = *(const uint4*)o;
}

// ------ fused dual-side SAGE conv GEMM, NO LDS (direct-global weights) ----
struct SideParams {
    const u16* A1b; const u16* W1T;
    const u16* A2b; const u16* W2T;
    const float* bias; u16* out;
    int M; int do_relu; int nblocks;
};
__global__ __launch_bounds__(256) void conv_nl(SideParams sa, SideParams sd) {
    const bool isA = (int)blockIdx.x < sa.nblocks;
    SideParams P = isA ? sa : sd;
    const int bx = isA ? blockIdx.x : blockIdx.x - sa.nblocks;
    const int tid = threadIdx.x;
    const int lane = tid & 63, wave = tid >> 6;
    const int r15 = lane & 15, kq = lane >> 4;
    const int rowbase = bx * 128 + wave * 32;
    const int m0 = rowbase + r15, m1 = rowbase + 16 + r15;
    const bool v0 = rowbase < P.M, v1 = rowbase + 16 < P.M;   // M % 16 == 0

    vf32x4 acc0[8], acc1[8];
#pragma unroll
    for (int i = 0; i < 8; ++i) { acc0[i] = (vf32x4)(0.0f); acc1[i] = (vf32x4)(0.0f); }

#pragma unroll
    for (int mat = 0; mat < 2; ++mat) {
        const u16* WT = mat ? P.W2T : P.W1T;
        const u16* Ab = mat ? P.A2b : P.A1b;
#pragma unroll
        for (int ks = 0; ks < 4; ++ks) {
            vbf16x8 a0 = (vbf16x8)(short)0, a1 = (vbf16x8)(short)0;
            if (v0) a0 = *(const vbf16x8*)(Ab + (size_t)m0 * 128 + ks * 32 + kq * 8);
            if (v1) a1 = *(const vbf16x8*)(Ab + (size_t)m1 * 128 + ks * 32 + kq * 8);
#pragma unroll
            for (int nt = 0; nt < 8; ++nt) {
                vbf16x8 b = bfrag(WT, nt, r15, ks, kq);
                acc0[nt] = __builtin_amdgcn_mfma_f32_16x16x32_bf16(a0, b, acc0[nt], 0, 0, 0);
                acc1[nt] = __builtin_amdgcn_mfma_f32_16x16x32_bf16(a1, b, acc1[nt], 0, 0, 0);
            }
        }
    }

#pragma unroll
    for (int nt = 0; nt < 8; ++nt) {
        const float bv = P.bias[nt * 16 + r15];
#pragma unroll
        for (int r = 0; r < 4; ++r) {
            if (v0) {
                float v = acc0[nt][r] + bv;
                if (P.do_relu) v = fmaxf(v, 0.0f);
                P.out[(size_t)(rowbase + kq * 4 + r) * 128 + nt * 16 + r15] = f2bf(v);
            }
            if (v1) {
                float v = acc1[nt][r] + bv;
                if (P.do_relu) v = fmaxf(v, 0.0f);
                P.out[(size_t)(rowbase + 16 + kq * 4 + r) * 128 + nt * 16 + r15] = f2bf(v);
            }
        }
    }
}

// ---------------- edge scorer: pred[e] = dot(od[i0[e]], oa[i1[e]]) --------
__global__ __launch_bounds__(256) void edge_dot(
    const u16* __restrict__ od, const u16* __restrict__ oa,
    const int* __restrict__ i0, const int* __restrict__ i1,
    float* __restrict__ pred, int EL) {
    int gid = blockIdx.x * 256 + threadIdx.x;
    if (gid >= EL * 16) return;
    int e = gid >> 4, f = gid & 15;
    uint4 x = *(const uint4*)(od + (size_t)i0[e] * 128 + f * 8);
    uint4 y = *(const uint4*)(oa + (size_t)i1[e] * 128 + f * 8);
    float s = 0.0f;
    s += bf2f((u16)(x.x & 0xffff)) * bf2f((u16)(y.x & 0xffff));
    s += bf2f((u16)(x.x >> 16))    * bf2f((u16)(y.x >> 16));
    s += bf2f((u16)(x.y & 0xffff)) * bf2f((u16)(y.y & 0xffff));
    s += bf2f((u16)(x.y >> 16))    * bf2f((u16)(y.y >> 16));
    s += bf2f((u16)(x.z & 0xffff)) * bf2f((u16)(y.z & 0xffff));
    s += bf2f((u16)(x.z >> 16))    * bf2f((u16)(y.z >> 16));
    s += bf2f((u16)(x.w & 0xffff)) * bf2f((u16)(y.w & 0xffff));
    s += bf2f((u16)(x.w >> 16))    * bf2f((u16)(y.w >> 16));
    s += __shfl_xor(s, 1);
    s += __shfl_xor(s, 2);
    s += __shfl_xor(s, 4);
    s += __shfl_xor(s, 8);
    if (f == 0) pred[e] = s;
}

extern "C" void kernel_launch(void* const* d_in, const int* in_sizes, int n_in,
                              void* d_out, int out_size, void* d_ws, size_t ws_size,
                              hipStream_t stream) {
    const float* doc_x    = (const float*)d_in[0];
    const int*   auth_id  = (const int*)d_in[1];
    const int*   eidx     = (const int*)d_in[2];
    const int*   elidx    = (const int*)d_in[3];
    const float* W_doc    = (const float*)d_in[4];
    const float* b_doc    = (const float*)d_in[5];
    const float* emb      = (const float*)d_in[6];
    const float* c1_da_Wl = (const float*)d_in[7];
    const float* c1_da_bl = (const float*)d_in[8];
    const float* c1_da_Wr = (const float*)d_in[9];
    const float* c1_ad_Wl = (const float*)d_in[10];
    const float* c1_ad_bl = (const float*)d_in[11];
    const float* c1_ad_Wr = (const float*)d_in[12];
    const float* c2_da_Wl = (const float*)d_in[13];
    const float* c2_da_bl = (const float*)d_in[14];
    const float* c2_da_Wr = (const float*)d_in[15];
    const float* c2_ad_Wl = (const float*)d_in[16];
    const float* c2_ad_bl = (const float*)d_in[17];
    const float* c2_ad_Wr = (const float*)d_in[18];

    const int ND = in_sizes[0] / 128;
    const int NA = in_sizes[1];
    const int E  = in_sizes[2] / 2;
    const int EL = in_sizes[3] / 2;
    const int* e_src = eidx;        // doc endpoints
    const int* e_dst = eidx + E;    // author endpoints
    const int BA = (NA + 127) / 128, BD = (ND + 127) / 128;   // 128-row tiles
    const int gatherB = (NA * 16 + 255) / 256;

    // ---- workspace layout ----
    char* base = (char*)d_ws;
    size_t off = 0;
    auto alloc = [&](size_t bytes) {
        void* p = base + off;
        off = (off + bytes + 255) & ~(size_t)255;
        return p;
    };
    u16*  xdoc  = (u16*)alloc((size_t)ND * 128 * 2);   // later reused as o_d
    u16*  xauth = (u16*)alloc((size_t)NA * 128 * 2);   // later reused as o_a
    u16*  hd    = (u16*)alloc((size_t)ND * 128 * 2);
    u16*  ha    = (u16*)alloc((size_t)NA * 128 * 2);
    u16*  aggA  = (u16*)alloc((size_t)NA * 128 * 2);
    u16*  aggD  = (u16*)alloc((size_t)ND * 128 * 2);
    u16*  wt    = (u16*)alloc((size_t)9 * 128 * 128 * 2);
    int*  cnt   = (int*)alloc((size_t)(ND + NA) * 4);
    int*  offs_d = (int*)alloc((size_t)(ND + 1) * 4);
    int*  offs_a = (int*)alloc((size_t)(NA + 1) * 4);
    int*  nbr_d = (int*)alloc((size_t)E * 4);
    int*  nbr_a = (int*)alloc((size_t)E * 4);
    int*  cntD  = (int*)alloc((size_t)NBUK * NBLK_BIN * 4);
    int*  cntA  = (int*)alloc((size_t)NBUK * NBLK_BIN * 4);
    int*  btot  = (int*)alloc((size_t)2 * NBUK * 4);
    uint2* ovfD = (uint2*)alloc((size_t)OVFCAP * 8);
    uint2* ovfA = (uint2*)alloc((size_t)OVFCAP * 8);
    int*  ovfn  = (int*)alloc(256);
    (void)ws_size; (void)n_in; (void)out_size;
    u16* od = xdoc;   // layer-2 outputs overwrite layer-0 features
    u16* oa = xauth;
    // staging aliases aggD/aggA: dead until first agg_mean2 (stream-ordered
    // after bucket_fill3). NBUK*NBLK_BIN*SCAP*4 = 6.29 MB each.
    unsigned* stageD = (unsigned*)aggD;
    unsigned* stageA = (unsigned*)aggA;

    TPack tp;
    const float* srcs[9] = {W_doc, c1_da_Wl, c1_da_Wr, c1_ad_Wl, c1_ad_Wr,
                            c2_da_Wl, c2_da_Wr, c2_ad_Wl, c2_ad_Wr};
    for (int i = 0; i < 9; ++i) { tp.src[i] = srcs[i]; tp.dst[i] = wt + (size_t)i * 16384; }
    const u16 *WTdoc = wt, *WT_c1daL = wt + 16384, *WT_c1daR = wt + 2 * 16384,
              *WT_c1adL = wt + 3 * 16384, *WT_c1adR = wt + 4 * 16384,
              *WT_c2daL = wt + 5 * 16384, *WT_c2daR = wt + 6 * 16384,
              *WT_c2adL = wt + 7 * 16384, *WT_c2adR = wt + 8 * 16384;

    // bucket shifts: smallest s with ((N-1)>>s) < NBUK  (range = 1<<s <= 1024)
    int shD = 0; while (((ND - 1) >> shD) >= NBUK) ++shD;
    int shA = 0; while (((NA - 1) >> shA) >= NBUK) ++shA;

    // ---- 1) weight transposes + ovfn zero ----
    wtp<<<576, 256, 0, stream>>>(tp, ovfn);

    // ---- 2) doc GEMM ∥ edge binning ∥ author gather (one dispatch) ----
    mega2<<<BD + 2 * NBLK_BIN + gatherB, 256, 0, stream>>>(
        doc_x, WTdoc, b_doc, xdoc, ND, BD,
        emb, auth_id, xauth, NA,
        e_src, e_dst, stageD, stageA, cntD, cntA, ovfD, ovfA, ovfn,
        E, shD, shA);

    // ---- 3) per-node counts + per-bucket totals ----
    bucket_count2<<<2 * NBUK, 256, 0, stream>>>(
        stageD, stageA, cntD, cntA, ovfD, ovfA, ovfn,
        cnt, cnt + ND, btot, ND, NA, shD, shA);

    // ---- 4) bucket-level exclusive scan ----
    scanb<<<1, 256, 0, stream>>>(btot);

    // ---- 5) node-level scan (offs) + nbr fill, per bucket ----
    bucket_fill3<<<2 * NBUK, 256, 0, stream>>>(
        stageD, stageA, cntD, cntA, ovfD, ovfA, ovfn,
        cnt, cnt + ND, btot, offs_d, offs_a, nbr_d, nbr_a,
        ND, NA, shD, shA);

    const int aggGrid = ((NA + ND) * 16 + 255) / 256;

    // ---- layer 1 (relu) ----
    agg_mean2<<<aggGrid, 256, 0, stream>>>(
        xdoc, offs_a, nbr_a, aggA, NA, xauth, offs_d, nbr_d, aggD, ND);
    {
        SideParams sa = {aggA, WT_c1daL, xauth, WT_c1daR, c1_da_bl, ha, NA, 1, BA};
        SideParams sd = {aggD, WT_c1adL, xdoc,  WT_c1adR, c1_ad_bl, hd, ND, 1, BD};
        conv_nl<<<BA + BD, 256, 0, stream>>>(sa, sd);
    }

    // ---- layer 2 ----
    agg_mean2<<<aggGrid, 256, 0, stream>>>(
        hd, offs_a, nbr_a, aggA, NA, ha, offs_d, nbr_d, aggD, ND);
    {
        SideParams sa = {aggA, WT_c2daL, ha, WT_c2daR, c2_da_bl, oa, NA, 0, BA};
        SideParams sd = {aggD, WT_c2adL, hd, WT_c2adR, c2_ad_bl, od, ND, 0, BD};
        conv_nl<<<BA + BD, 256, 0, stream>>>(sa, sd);
    }

    // ---- edge scorer ----
    edge_dot<<<(EL * 16 + 255) / 256, 256, 0, stream>>>(
        od, oa, elidx, elidx + EL, (float*)d_out, EL);
}

// Round 11
// 354.330 us; speedup vs baseline: 1.2587x; 1.2587x over previous
//
#include <hip/hip_runtime.h>

typedef unsigned short u16;
typedef __attribute__((ext_vector_type(8))) short vbf16x8;   // 8 bf16 (4 VGPRs)
typedef __attribute__((ext_vector_type(4))) float vf32x4;    // MFMA acc frag

__device__ __forceinline__ float bf2f(u16 u) {
    union { unsigned int i; float f; } v; v.i = ((unsigned int)u) << 16; return v.f;
}
__device__ __forceinline__ u16 f2bf(float f) {
    union { float f; unsigned int i; } v; v.f = f;
    return (u16)((v.i + 0x7fffu + ((v.i >> 16) & 1u)) >> 16);  // RNE
}

struct TPack { const float* src[9]; u16* dst[9]; };

// ============== bucketed CSR build constants ==============
#define NBUK 256
#define NBLK_BIN 256
#define SCAP 24
#define OVFCAP 32768
#define PACK_SH 17   // staged word = (local_key << 17) | val ; val < 2^17

// ---- 9 weight transposes (576 blocks) + ovfn zero (replaces memset) ----
__global__ __launch_bounds__(256) void wtp(TPack p, int* __restrict__ ovfn) {
    int b = blockIdx.x;
    if (b == 0 && threadIdx.x < 2) ovfn[threadIdx.x] = 0;
    int mat = b >> 6;
    const float* s = p.src[mat];
    u16* d = p.dst[mat];
    int i = (b & 63) * 256 + threadIdx.x;
    int k = i >> 7, n = i & 127;
    d[(size_t)n * 128 + k] = f2bf(s[(size_t)k * 128 + n]);
}

// ===== mega2: doc GEMM tiles  ∥  edge bin-scatter  ∥  author gather ======
// All three are mutually independent; fusing them into one dispatch overlaps
// their latency stalls (each alone runs with <15% pipe utilization).
__global__ __launch_bounds__(256) void mega2(
    // doc gemm
    const float* __restrict__ A1f, const u16* __restrict__ W1T,
    const float* __restrict__ biasd, u16* __restrict__ xdoc, int M, int BD,
    // author gather
    const float* __restrict__ emb, const int* __restrict__ ids,
    u16* __restrict__ xauth, int NA,
    // edge binning
    const int* __restrict__ src, const int* __restrict__ dst,
    unsigned* __restrict__ stageD, unsigned* __restrict__ stageA,
    int* __restrict__ cntD, int* __restrict__ cntA,
    uint2* __restrict__ ovfD, uint2* __restrict__ ovfA, int* __restrict__ ovfn,
    int E, int shD, int shA) {
    __shared__ u16 WS[128 * 128];   // 32 KB (GEMM); aliased as lcnt (binning)
    const int b = blockIdx.x;
    const int tid = threadIdx.x;

    if (b < BD) {                          // ---- doc encoder GEMM tile ----
        const int lane = tid & 63, wave = tid >> 6;
        const int r15 = lane & 15, kq = lane >> 4;
        const int rowbase = b * 128 + wave * 32;
        const int m0 = rowbase + r15, m1 = rowbase + 16 + r15;
        const bool v0 = rowbase < M, v1 = rowbase + 16 < M;

        vf32x4 acc0[8], acc1[8];
#pragma unroll
        for (int i = 0; i < 8; ++i) { acc0[i] = (vf32x4)(0.0f); acc1[i] = (vf32x4)(0.0f); }

#pragma unroll
        for (int i = 0; i < 8; ++i) {
            int L = i * 256 + tid;
            int n = L >> 4, bk = L & 15;
            *(uint4*)(WS + ((size_t)n * 16 + (bk ^ (n & 15))) * 8) =
                *(const uint4*)(W1T + (size_t)L * 8);
        }
        __syncthreads();

#pragma unroll
        for (int ks = 0; ks < 4; ++ks) {
            vbf16x8 a0 = (vbf16x8)(short)0, a1 = (vbf16x8)(short)0;
            if (v0) {
                const float* p = A1f + (size_t)m0 * 128 + ks * 32 + kq * 8;
                float4 lo = *(const float4*)p, hi = *(const float4*)(p + 4);
                a0[0] = (short)f2bf(lo.x); a0[1] = (short)f2bf(lo.y);
                a0[2] = (short)f2bf(lo.z); a0[3] = (short)f2bf(lo.w);
                a0[4] = (short)f2bf(hi.x); a0[5] = (short)f2bf(hi.y);
                a0[6] = (short)f2bf(hi.z); a0[7] = (short)f2bf(hi.w);
            }
            if (v1) {
                const float* p = A1f + (size_t)m1 * 128 + ks * 32 + kq * 8;
                float4 lo = *(const float4*)p, hi = *(const float4*)(p + 4);
                a1[0] = (short)f2bf(lo.x); a1[1] = (short)f2bf(lo.y);
                a1[2] = (short)f2bf(lo.z); a1[3] = (short)f2bf(lo.w);
                a1[4] = (short)f2bf(hi.x); a1[5] = (short)f2bf(hi.y);
                a1[6] = (short)f2bf(hi.z); a1[7] = (short)f2bf(hi.w);
            }
#pragma unroll
            for (int nt = 0; nt < 8; ++nt) {
                vbf16x8 bb = *(const vbf16x8*)(
                    WS + ((size_t)(nt * 16 + r15) * 16 + ((ks * 4 + kq) ^ r15)) * 8);
                acc0[nt] = __builtin_amdgcn_mfma_f32_16x16x32_bf16(a0, bb, acc0[nt], 0, 0, 0);
                acc1[nt] = __builtin_amdgcn_mfma_f32_16x16x32_bf16(a1, bb, acc1[nt], 0, 0, 0);
            }
        }

#pragma unroll
        for (int nt = 0; nt < 8; ++nt) {
            const float bv = biasd[nt * 16 + r15];
#pragma unroll
            for (int r = 0; r < 4; ++r) {
                if (v0) xdoc[(size_t)(rowbase + kq * 4 + r) * 128 + nt * 16 + r15] =
                    f2bf(acc0[nt][r] + bv);
                if (v1) xdoc[(size_t)(rowbase + 16 + kq * 4 + r) * 128 + nt * 16 + r15] =
                    f2bf(acc1[nt][r] + bv);
            }
        }
        return;
    }

    if (b < BD + 2 * NBLK_BIN) {           // ---- edge binning ----
        int* lcnt = (int*)WS;              // alias GEMM LDS
        int bb = b - BD;
        const bool isD = bb < NBLK_BIN;
        const int blk = isD ? bb : bb - NBLK_BIN;
        const int* key = isD ? src : dst;
        const int* val = isD ? dst : src;
        const int shift = isD ? shD : shA;
        unsigned* stage = isD ? stageD : stageA;
        int* cnt = isD ? cntD : cntA;
        uint2* ovf = isD ? ovfD : ovfA;
        int* on = ovfn + (isD ? 0 : 1);
        const int per = (E + NBLK_BIN - 1) / NBLK_BIN;
        const int beg = blk * per;
        const int end = min(beg + per, E);
        for (int i = tid; i < NBUK; i += 256) lcnt[i] = 0;
        __syncthreads();
        for (int e = beg + tid; e < end; e += 256) {
            int k = key[e], v = val[e];
            int bkt = k >> shift;
            int slot = atomicAdd(&lcnt[bkt], 1);
            if (slot < SCAP) {
                unsigned local = (unsigned)(k - (bkt << shift));
                stage[((size_t)bkt * NBLK_BIN + blk) * SCAP + slot] =
                    (local << PACK_SH) | (unsigned)v;
            } else {                       // rare: spill to overflow list
                int oi = atomicAdd(on, 1);
                if (oi < OVFCAP) ovf[oi] = make_uint2((unsigned)k, (unsigned)v);
            }
        }
        __syncthreads();
        for (int i = tid; i < NBUK; i += 256)
            cnt[(size_t)i * NBLK_BIN + blk] = min(lcnt[i], SCAP);
        return;
    }

    // ---- author row gather ----
    int gid = (b - BD - 2 * NBLK_BIN) * 256 + tid;
    if (gid >= NA * 16) return;
    int n = gid >> 4, f = gid & 15;
    int id = ids[n];
    const float* s = emb + (size_t)id * 128 + f * 8;
    float4 lo = *(const float4*)(s);
    float4 hi = *(const float4*)(s + 4);
    u16 o[8] = {f2bf(lo.x), f2bf(lo.y), f2bf(lo.z), f2bf(lo.w),
                f2bf(hi.x), f2bf(hi.y), f2bf(hi.z), f2bf(hi.w)};
    *(uint4*)(xauth + (size_t)n * 128 + f * 8) = *(const uint4*)o;
}

// ---- per-bucket LDS histogram -> per-node counts + per-bucket totals ----
__global__ __launch_bounds__(256) void bucket_count2(
    const unsigned* __restrict__ stageD, const unsigned* __restrict__ stageA,
    const int* __restrict__ cntD, const int* __restrict__ cntA,
    const uint2* __restrict__ ovfD, const uint2* __restrict__ ovfA,
    const int* __restrict__ ovfn,
    int* __restrict__ cnt_d, int* __restrict__ cnt_a, int* __restrict__ btot,
    int ND, int NA, int shD, int shA) {
    __shared__ int hist[1024];
    __shared__ int segc[NBLK_BIN];
    __shared__ int red[256];
    const bool isD = (int)blockIdx.x < NBUK;
    const int b = isD ? (int)blockIdx.x : (int)blockIdx.x - NBUK;
    const int sh = isD ? shD : shA;
    const int N = isD ? ND : NA;
    const int base = b << sh;
    const int range = min(1 << sh, N - base);
    const int tid = threadIdx.x;
    if (range <= 0) { if (tid == 0) btot[blockIdx.x] = 0; return; }
    const unsigned* stage = (isD ? stageD : stageA) + (size_t)b * NBLK_BIN * SCAP;
    const int* scnt = (isD ? cntD : cntA) + (size_t)b * NBLK_BIN;
    const uint2* ovf = isD ? ovfD : ovfA;
    const int nov = min(ovfn[isD ? 0 : 1], OVFCAP);
    int* out = isD ? cnt_d : cnt_a;
    for (int i = tid; i < (1 << sh); i += 256) hist[i] = 0;
    segc[tid] = scnt[tid];
    __syncthreads();
    int my = 0;
    for (int j = tid; j < NBLK_BIN * SCAP; j += 256) {
        int seg = j / SCAP, slot = j - seg * SCAP;
        if (slot < segc[seg]) { atomicAdd(&hist[stage[j] >> PACK_SH], 1); ++my; }
    }
    for (int i = tid; i < nov; i += 256) {
        int k = (int)ovf[i].x;
        if ((k >> sh) == b) { atomicAdd(&hist[k - base], 1); ++my; }
    }
    red[tid] = my;
    __syncthreads();
    for (int s = 128; s > 0; s >>= 1) {
        if (tid < s) red[tid] += red[tid + s];
        __syncthreads();
    }
    if (tid == 0) btot[blockIdx.x] = red[0];
    for (int i = tid; i < range; i += 256) out[base + i] = hist[i];
}

// ---- single-block exclusive scan over per-bucket totals (both sides) ----
__global__ __launch_bounds__(256) void scanb(int* __restrict__ btot) {
    __shared__ int sh[256];
    const int tid = threadIdx.x;
    for (int seg = 0; seg < 2; ++seg) {
        int* p = btot + seg * NBUK;
        int v = p[tid];
        sh[tid] = v;
        __syncthreads();
        for (int off = 1; off < 256; off <<= 1) {
            int t = tid >= off ? sh[tid - off] : 0;
            __syncthreads();
            sh[tid] += t;
            __syncthreads();
        }
        p[tid] = sh[tid] - v;   // exclusive
        __syncthreads();
    }
}

// ---- per-bucket: node-level LDS scan -> offs, then nbr fill -------------
__global__ __launch_bounds__(256) void bucket_fill3(
    const unsigned* __restrict__ stageD, const unsigned* __restrict__ stageA,
    const int* __restrict__ cntD, const int* __restrict__ cntA,
    const uint2* __restrict__ ovfD, const uint2* __restrict__ ovfA,
    const int* __restrict__ ovfn,
    const int* __restrict__ cnt_d, const int* __restrict__ cnt_a,
    const int* __restrict__ btot,
    int* __restrict__ offs_d, int* __restrict__ offs_a,
    int* __restrict__ nbr_d, int* __restrict__ nbr_a,
    int ND, int NA, int shD, int shA) {
    __shared__ int lcur[1024];
    __shared__ int segc[NBLK_BIN];
    __shared__ int sh[256];
    __shared__ int carry;
    const bool isD = (int)blockIdx.x < NBUK;
    const int b = isD ? (int)blockIdx.x : (int)blockIdx.x - NBUK;
    const int shft = isD ? shD : shA;
    const int N = isD ? ND : NA;
    const int base = b << shft;
    const int range = min(1 << shft, N - base);
    if (range <= 0) return;
    const unsigned* stage = (isD ? stageD : stageA) + (size_t)b * NBLK_BIN * SCAP;
    const int* scnt = (isD ? cntD : cntA) + (size_t)b * NBLK_BIN;
    const uint2* ovf = isD ? ovfD : ovfA;
    const int nov = min(ovfn[isD ? 0 : 1], OVFCAP);
    const int* cnodes = isD ? cnt_d : cnt_a;
    int* offs = isD ? offs_d : offs_a;
    int* nbr = isD ? nbr_d : nbr_a;
    const int tid = threadIdx.x;
    segc[tid] = scnt[tid];
    if (tid == 0) carry = btot[blockIdx.x];   // exclusive bucket base
    __syncthreads();
    // chunked exclusive scan of per-node counts -> offs + LDS cursors
    for (int c0 = 0; c0 < range; c0 += 256) {
        int i = c0 + tid;
        int v = (i < range) ? cnodes[base + i] : 0;
        sh[tid] = v;
        __syncthreads();
        for (int off = 1; off < 256; off <<= 1) {
            int t = tid >= off ? sh[tid - off] : 0;
            __syncthreads();
            sh[tid] += t;
            __syncthreads();
        }
        if (i < range) {
            int ex = carry + sh[tid] - v;
            lcur[i] = ex;
            offs[base + i] = ex;
        }
        __syncthreads();
        if (tid == 255) carry += sh[255];
        __syncthreads();
    }
    if (tid == 0) offs[base + range] = carry;  // duplicate of next bucket's base
    __syncthreads();
    // fill
    for (int j = tid; j < NBLK_BIN * SCAP; j += 256) {
        int seg = j / SCAP, slot = j - seg * SCAP;
        if (slot < segc[seg]) {
            unsigned pk = stage[j];
            int local = pk >> PACK_SH;
            int v = (int)(pk & ((1u << PACK_SH) - 1u));
            nbr[atomicAdd(&lcur[local], 1)] = v;
        }
    }
    for (int i = tid; i < nov; i += 256) {
        int k = (int)ovf[i].x;
        if ((k >> shft) == b)
            nbr[atomicAdd(&lcur[k - base], 1)] = (int)ovf[i].y;
    }
}

// ================= fused gather mean-aggregation (both sides) =============
__global__ __launch_bounds__(256) void agg_mean2(
    const u16* __restrict__ xa, const int* __restrict__ offs_a,
    const int* __restrict__ nbr_a, u16* __restrict__ outa, int NA,
    const u16* __restrict__ xd, const int* __restrict__ offs_d,
    const int* __restrict__ nbr_d, u16* __restrict__ outd, int ND) {
    int gid = blockIdx.x * 256 + threadIdx.x;
    int node = gid >> 4, f = gid & 15;
    int lane = threadIdx.x & 63;
    int gbase = lane & 48;                 // group base lane within wave
    const u16* x; const int* offs; const int* nbr; u16* out;
    if (node < NA) { x = xa; offs = offs_a; nbr = nbr_a; out = outa; }
    else {
        node -= NA;
        if (node >= ND) return;
        x = xd; offs = offs_d; nbr = nbr_d; out = outd;
    }
    int beg = offs[node], end = offs[node + 1];
    float acc[8] = {0, 0, 0, 0, 0, 0, 0, 0};

    for (int i = beg; i < end; i += 16) {
        int cnt = end - i; if (cnt > 16) cnt = 16;
        int myn = (i + f < end) ? nbr[i + f] : 0;
        int t = 0;
        for (; t + 3 < cnt; t += 4) {      // 4 row-gathers in flight
            int i0 = __shfl(myn, gbase + t);
            int i1 = __shfl(myn, gbase + t + 1);
            int i2 = __shfl(myn, gbase + t + 2);
            int i3 = __shfl(myn, gbase + t + 3);
            uint4 q0 = *(const uint4*)(x + (size_t)i0 * 128 + f * 8);
            uint4 q1 = *(const uint4*)(x + (size_t)i1 * 128 + f * 8);
            uint4 q2 = *(const uint4*)(x + (size_t)i2 * 128 + f * 8);
            uint4 q3 = *(const uint4*)(x + (size_t)i3 * 128 + f * 8);
            acc[0] += bf2f((u16)(q0.x & 0xffff)) + bf2f((u16)(q1.x & 0xffff))
                    + bf2f((u16)(q2.x & 0xffff)) + bf2f((u16)(q3.x & 0xffff));
            acc[1] += bf2f((u16)(q0.x >> 16))    + bf2f((u16)(q1.x >> 16))
                    + bf2f((u16)(q2.x >> 16))    + bf2f((u16)(q3.x >> 16));
            acc[2] += bf2f((u16)(q0.y & 0xffff)) + bf2f((u16)(q1.y & 0xffff))
                    + bf2f((u16)(q2.y & 0xffff)) + bf2f((u16)(q3.y & 0xffff));
            acc[3] += bf2f((u16)(q0.y >> 16))    + bf2f((u16)(q1.y >> 16))
                    + bf2f((u16)(q2.y >> 16))    + bf2f((u16)(q3.y >> 16));
            acc[4] += bf2f((u16)(q0.z & 0xffff)) + bf2f((u16)(q1.z & 0xffff))
                    + bf2f((u16)(q2.z & 0xffff)) + bf2f((u16)(q3.z & 0xffff));
            acc[5] += bf2f((u16)(q0.z >> 16))    + bf2f((u16)(q1.z >> 16))
                    + bf2f((u16)(q2.z >> 16))    + bf2f((u16)(q3.z >> 16));
            acc[6] += bf2f((u16)(q0.w & 0xffff)) + bf2f((u16)(q1.w & 0xffff))
                    + bf2f((u16)(q2.w & 0xffff)) + bf2f((u16)(q3.w & 0xffff));
            acc[7] += bf2f((u16)(q0.w >> 16))    + bf2f((u16)(q1.w >> 16))
                    + bf2f((u16)(q2.w >> 16))    + bf2f((u16)(q3.w >> 16));
        }
        for (; t < cnt; ++t) {
            int i0 = __shfl(myn, gbase + t);
            uint4 q0 = *(const uint4*)(x + (size_t)i0 * 128 + f * 8);
            acc[0] += bf2f((u16)(q0.x & 0xffff));
            acc[1] += bf2f((u16)(q0.x >> 16));
            acc[2] += bf2f((u16)(q0.y & 0xffff));
            acc[3] += bf2f((u16)(q0.y >> 16));
            acc[4] += bf2f((u16)(q0.z & 0xffff));
            acc[5] += bf2f((u16)(q0.z >> 16));
            acc[6] += bf2f((u16)(q0.w & 0xffff));
            acc[7] += bf2f((u16)(q0.w >> 16));
        }
    }
    float inv = 1.0f / fmaxf((float)(end - beg), 1.0f);
    u16 o[8];
#pragma unroll
    for (int j = 0; j < 8; ++j) o[j] = f2bf(acc[j] * inv);
    *(uint4*)(out + (size_t)node * 128 + f * 8) = *(const uint4*)o;
}

// --- fused dual-side SAGE conv GEMM: persistent weights + prefetch -------
struct SideParams3 {
    const u16* A1b; const u16* W1T;
    const u16* A2b; const u16* W2T;
    const float* bias; u16* out;
    int M; int do_relu; int ntiles; int gblocks;
};
__global__ __launch_bounds__(256) void conv_gemm3(SideParams3 sa, SideParams3 sd) {
    __shared__ u16 WS[2 * 128 * 128];   // 64 KB: both weight mats, staged ONCE
    const bool isA = (int)blockIdx.x < sa.gblocks;
    SideParams3 P = isA ? sa : sd;
    const int gb = isA ? (int)blockIdx.x : (int)blockIdx.x - sa.gblocks;
    const int tid = threadIdx.x;
    const int lane = tid & 63, wave = tid >> 6;
    const int r15 = lane & 15, kq = lane >> 4;

#pragma unroll
    for (int i = 0; i < 8; ++i) {
        int L = i * 256 + tid;
        int n = L >> 4, bk = L & 15;
        *(uint4*)(WS + ((size_t)n * 16 + (bk ^ (n & 15))) * 8) =
            *(const uint4*)(P.W1T + (size_t)L * 8);
        *(uint4*)(WS + 16384 + ((size_t)n * 16 + (bk ^ (n & 15))) * 8) =
            *(const uint4*)(P.W2T + (size_t)L * 8);
    }
    __syncthreads();
    float bv[8];
#pragma unroll
    for (int nt = 0; nt < 8; ++nt) bv[nt] = P.bias[nt * 16 + r15];

    auto loadA = [&](const u16* Ab, int tile, vbf16x8* fa, vbf16x8* fb) {
        const int rowbase = tile * 128 + wave * 32;
        const int m0 = rowbase + r15, m1 = rowbase + 16 + r15;
        const bool v0 = rowbase < P.M, v1 = rowbase + 16 < P.M;
#pragma unroll
        for (int ks = 0; ks < 4; ++ks) {
            fa[ks] = v0 ? *(const vbf16x8*)(Ab + (size_t)m0 * 128 + ks * 32 + kq * 8)
                        : (vbf16x8)(short)0;
            fb[ks] = v1 ? *(const vbf16x8*)(Ab + (size_t)m1 * 128 + ks * 32 + kq * 8)
                        : (vbf16x8)(short)0;
        }
    };

    vbf16x8 c1a[4], c1b[4], c2a[4], c2b[4], n1a[4], n1b[4];
    if (gb < P.ntiles) loadA(P.A1b, gb, c1a, c1b);
    for (int t = gb; t < P.ntiles; t += P.gblocks) {
        loadA(P.A2b, t, c2a, c2b);              // issue, consumed after mat1
        const int tn = t + P.gblocks;
        if (tn < P.ntiles) loadA(P.A1b, tn, n1a, n1b);   // prefetch next tile

        vf32x4 acc0[8], acc1[8];
#pragma unroll
        for (int i = 0; i < 8; ++i) { acc0[i] = (vf32x4)(0.0f); acc1[i] = (vf32x4)(0.0f); }
#pragma unroll
        for (int ks = 0; ks < 4; ++ks) {
#pragma unroll
            for (int nt = 0; nt < 8; ++nt) {
                vbf16x8 b = *(const vbf16x8*)(
                    WS + ((size_t)(nt * 16 + r15) * 16 + ((ks * 4 + kq) ^ r15)) * 8);
                acc0[nt] = __builtin_amdgcn_mfma_f32_16x16x32_bf16(c1a[ks], b, acc0[nt], 0, 0, 0);
                acc1[nt] = __builtin_amdgcn_mfma_f32_16x16x32_bf16(c1b[ks], b, acc1[nt], 0, 0, 0);
            }
        }
#pragma unroll
        for (int ks = 0; ks < 4; ++ks) {
#pragma unroll
            for (int nt = 0; nt < 8; ++nt) {
                vbf16x8 b = *(const vbf16x8*)(
                    WS + 16384 + ((size_t)(nt * 16 + r15) * 16 + ((ks * 4 + kq) ^ r15)) * 8);
                acc0[nt] = __builtin_amdgcn_mfma_f32_16x16x32_bf16(c2a[ks], b, acc0[nt], 0, 0, 0);
                acc1[nt] = __builtin_amdgcn_mfma_f32_16x16x32_bf16(c2b[ks], b, acc1[nt], 0, 0, 0);
            }
        }

        const int rowbase = t * 128 + wave * 32;
        const bool v0 = rowbase < P.M, v1 = rowbase + 16 < P.M;
#pragma unroll
        for (int nt = 0; nt < 8; ++nt) {
#pragma unroll
            for (int r = 0; r < 4; ++r) {
                if (v0) {
                    float v = acc0[nt][r] + bv[nt];
                    if (P.do_relu) v = fmaxf(v, 0.0f);
                    P.out[(size_t)(rowbase + kq * 4 + r) * 128 + nt * 16 + r15] = f2bf(v);
                }
                if (v1) {
                    float v = acc1[nt][r] + bv[nt];
                    if (P.do_relu) v = fmaxf(v, 0.0f);
                    P.out[(size_t)(rowbase + 16 + kq * 4 + r) * 128 + nt * 16 + r15] = f2bf(v);
                }
            }
        }
#pragma unroll
        for (int ks = 0; ks < 4; ++ks) { c1a[ks] = n1a[ks]; c1b[ks] = n1b[ks]; }
    }
}

// ---------------- edge scorer: pred[e] = dot(od[i0[e]], oa[i1[e]]) --------
__global__ __launch_bounds__(256) void edge_dot(
    const u16* __restrict__ od, const u16* __restrict__ oa,
    const int* __restrict__ i0, const int* __restrict__ i1,
    float* __restrict__ pred, int EL) {
    int gid = blockIdx.x * 256 + threadIdx.x;
    if (gid >= EL * 16) return;
    int e = gid >> 4, f = gid & 15;
    uint4 x = *(const uint4*)(od + (size_t)i0[e] * 128 + f * 8);
    uint4 y = *(const uint4*)(oa + (size_t)i1[e] * 128 + f * 8);
    float s = 0.0f;
    s += bf2f((u16)(x.x & 0xffff)) * bf2f((u16)(y.x & 0xffff));
    s += bf2f((u16)(x.x >> 16))    * bf2f((u16)(y.x >> 16));
    s += bf2f((u16)(x.y & 0xffff)) * bf2f((u16)(y.y & 0xffff));
    s += bf2f((u16)(x.y >> 16))    * bf2f((u16)(y.y >> 16));
    s += bf2f((u16)(x.z & 0xffff)) * bf2f((u16)(y.z & 0xffff));
    s += bf2f((u16)(x.z >> 16))    * bf2f((u16)(y.z >> 16));
    s += bf2f((u16)(x.w & 0xffff)) * bf2f((u16)(y.w & 0xffff));
    s += bf2f((u16)(x.w >> 16))    * bf2f((u16)(y.w >> 16));
    s += __shfl_xor(s, 1);
    s += __shfl_xor(s, 2);
    s += __shfl_xor(s, 4);
    s += __shfl_xor(s, 8);
    if (f == 0) pred[e] = s;
}

extern "C" void kernel_launch(void* const* d_in, const int* in_sizes, int n_in,
                              void* d_out, int out_size, void* d_ws, size_t ws_size,
                              hipStream_t stream) {
    const float* doc_x    = (const float*)d_in[0];
    const int*   auth_id  = (const int*)d_in[1];
    const int*   eidx     = (const int*)d_in[2];
    const int*   elidx    = (const int*)d_in[3];
    const float* W_doc    = (const float*)d_in[4];
    const float* b_doc    = (const float*)d_in[5];
    const float* emb      = (const float*)d_in[6];
    const float* c1_da_Wl = (const float*)d_in[7];
    const float* c1_da_bl = (const float*)d_in[8];
    const float* c1_da_Wr = (const float*)d_in[9];
    const float* c1_ad_Wl = (const float*)d_in[10];
    const float* c1_ad_bl = (const float*)d_in[11];
    const float* c1_ad_Wr = (const float*)d_in[12];
    const float* c2_da_Wl = (const float*)d_in[13];
    const float* c2_da_bl = (const float*)d_in[14];
    const float* c2_da_Wr = (const float*)d_in[15];
    const float* c2_ad_Wl = (const float*)d_in[16];
    const float* c2_ad_bl = (const float*)d_in[17];
    const float* c2_ad_Wr = (const float*)d_in[18];

    const int ND = in_sizes[0] / 128;
    const int NA = in_sizes[1];
    const int E  = in_sizes[2] / 2;
    const int EL = in_sizes[3] / 2;
    const int* e_src = eidx;        // doc endpoints
    const int* e_dst = eidx + E;    // author endpoints
    const int BA = (NA + 127) / 128, BD = (ND + 127) / 128;   // 128-row tiles
    const int gatherB = (NA * 16 + 255) / 256;

    // ---- workspace layout ----
    char* base = (char*)d_ws;
    size_t off = 0;
    auto alloc = [&](size_t bytes) {
        void* p = base + off;
        off = (off + bytes + 255) & ~(size_t)255;
        return p;
    };
    u16*  xdoc  = (u16*)alloc((size_t)ND * 128 * 2);   // later reused as o_d
    u16*  xauth = (u16*)alloc((size_t)NA * 128 * 2);   // later reused as o_a
    u16*  hd    = (u16*)alloc((size_t)ND * 128 * 2);
    u16*  ha    = (u16*)alloc((size_t)NA * 128 * 2);
    u16*  aggA  = (u16*)alloc((size_t)NA * 128 * 2);
    u16*  aggD  = (u16*)alloc((size_t)ND * 128 * 2);
    u16*  wt    = (u16*)alloc((size_t)9 * 128 * 128 * 2);
    int*  cnt   = (int*)alloc((size_t)(ND + NA) * 4);
    int*  offs_d = (int*)alloc((size_t)(ND + 1) * 4);
    int*  offs_a = (int*)alloc((size_t)(NA + 1) * 4);
    int*  nbr_d = (int*)alloc((size_t)E * 4);
    int*  nbr_a = (int*)alloc((size_t)E * 4);
    int*  cntD  = (int*)alloc((size_t)NBUK * NBLK_BIN * 4);
    int*  cntA  = (int*)alloc((size_t)NBUK * NBLK_BIN * 4);
    int*  btot  = (int*)alloc((size_t)2 * NBUK * 4);
    uint2* ovfD = (uint2*)alloc((size_t)OVFCAP * 8);
    uint2* ovfA = (uint2*)alloc((size_t)OVFCAP * 8);
    int*  ovfn  = (int*)alloc(256);
    (void)ws_size; (void)n_in; (void)out_size;
    u16* od = xdoc;   // layer-2 outputs overwrite layer-0 features
    u16* oa = xauth;
    // staging aliases aggD/aggA: dead until first agg_mean2 (stream-ordered
    // after bucket_fill3). NBUK*NBLK_BIN*SCAP*4 = 6.29 MB each.
    unsigned* stageD = (unsigned*)aggD;
    unsigned* stageA = (unsigned*)aggA;

    TPack tp;
    const float* srcs[9] = {W_doc, c1_da_Wl, c1_da_Wr, c1_ad_Wl, c1_ad_Wr,
                            c2_da_Wl, c2_da_Wr, c2_ad_Wl, c2_ad_Wr};
    for (int i = 0; i < 9; ++i) { tp.src[i] = srcs[i]; tp.dst[i] = wt + (size_t)i * 16384; }
    const u16 *WTdoc = wt, *WT_c1daL = wt + 16384, *WT_c1daR = wt + 2 * 16384,
              *WT_c1adL = wt + 3 * 16384, *WT_c1adR = wt + 4 * 16384,
              *WT_c2daL = wt + 5 * 16384, *WT_c2daR = wt + 6 * 16384,
              *WT_c2adL = wt + 7 * 16384, *WT_c2adR = wt + 8 * 16384;

    // bucket shifts: smallest s with ((N-1)>>s) < NBUK  (range = 1<<s <= 1024)
    int shD = 0; while (((ND - 1) >> shD) >= NBUK) ++shD;
    int shA = 0; while (((NA - 1) >> shA) >= NBUK) ++shA;

    // ---- 1) weight transposes + ovfn zero ----
    wtp<<<576, 256, 0, stream>>>(tp, ovfn);

    // ---- 2) doc GEMM ∥ edge binning ∥ author gather (one dispatch) ----
    mega2<<<BD + 2 * NBLK_BIN + gatherB, 256, 0, stream>>>(
        doc_x, WTdoc, b_doc, xdoc, ND, BD,
        emb, auth_id, xauth, NA,
        e_src, e_dst, stageD, stageA, cntD, cntA, ovfD, ovfA, ovfn,
        E, shD, shA);

    // ---- 3) per-node counts + per-bucket totals ----
    bucket_count2<<<2 * NBUK, 256, 0, stream>>>(
        stageD, stageA, cntD, cntA, ovfD, ovfA, ovfn,
        cnt, cnt + ND, btot, ND, NA, shD, shA);

    // ---- 4) bucket-level exclusive scan ----
    scanb<<<1, 256, 0, stream>>>(btot);

    // ---- 5) node-level scan (offs) + nbr fill, per bucket ----
    bucket_fill3<<<2 * NBUK, 256, 0, stream>>>(
        stageD, stageA, cntD, cntA, ovfD, ovfA, ovfn,
        cnt, cnt + ND, btot, offs_d, offs_a, nbr_d, nbr_a,
        ND, NA, shD, shA);

    const int aggGrid = ((NA + ND) * 16 + 255) / 256;
    // conv grid split proportional to tiles; 512 blocks = 2/CU at 64 KB LDS
    const int gA = (int)(((long)512 * BA) / (BA + BD));
    const int gD = 512 - gA;

    // ---- layer 1 (relu) ----
    agg_mean2<<<aggGrid, 256, 0, stream>>>(
        xdoc, offs_a, nbr_a, aggA, NA, xauth, offs_d, nbr_d, aggD, ND);
    {
        SideParams3 sa = {aggA, WT_c1daL, xauth, WT_c1daR, c1_da_bl, ha, NA, 1, BA, gA};
        SideParams3 sd = {aggD, WT_c1adL, xdoc,  WT_c1adR, c1_ad_bl, hd, ND, 1, BD, gD};
        conv_gemm3<<<gA + gD, 256, 0, stream>>>(sa, sd);
    }

    // ---- layer 2 ----
    agg_mean2<<<aggGrid, 256, 0, stream>>>(
        hd, offs_a, nbr_a, aggA, NA, ha, offs_d, nbr_d, aggD, ND);
    {
        SideParams3 sa = {aggA, WT_c2daL, ha, WT_c2daR, c2_da_bl, oa, NA, 0, BA, gA};
        SideParams3 sd = {aggD, WT_c2adL, hd, WT_c2adR, c2_ad_bl, od, ND, 0, BD, gD};
        conv_gemm3<<<gA + gD, 256, 0, stream>>>(sa, sd);
    }

    // ---- edge scorer ----
    edge_dot<<<(EL * 16 + 255) / 256, 256, 0, stream>>>(
        od, oa, elidx, elidx + EL, (float*)d_out, EL);
}